// Round 4
// baseline (8336.115 us; speedup 1.0000x reference)
//
#include <hip/hip_runtime.h>

typedef short short8 __attribute__((ext_vector_type(8)));
typedef float f32x4 __attribute__((ext_vector_type(4)));
typedef unsigned int u32x4 __attribute__((ext_vector_type(4)));
typedef unsigned long long ull;

#define NB 64
#define NT 1024
#define NI 128
#define NH 512

// ws layout (bytes):
//   0        : M      512KB  combined recurrent matrix, bf16 [512][512]
//   524288   : WiT    128KB
//   655360   : X      128KB  h-half exchange: slot[(g*2+role)*8+w] x2 parity x 1KB
//   786432   : flags  4KB    per-slot uint, 64B stride
//   790528   : xcc    64B    per-bid xcc-id table
//   1048576  : xp     64MB   [t][b][256] f32
#define WS_X     655360
#define WS_FLAGS 786432
#define WS_XCC   790528
#define WS_XP    1048576

__device__ __forceinline__ unsigned short f2bf(float f) {
  union { float f; unsigned u; } v; v.f = f;
  unsigned u = v.u;
  return (unsigned short)((u + 0x7FFFu + ((u >> 16) & 1u)) >> 16);
}

__device__ __forceinline__ f32x4 mfma16(short8 a, short8 b, f32x4 c) {
  return __builtin_amdgcn_mfma_f32_16x16x32_bf16(a, b, c, 0, 0, 0);
}

__device__ __forceinline__ unsigned swzE(int m) {
  return (unsigned)(((m & 7) << 3) ^ ((m & 8) << 1));
}

union V128 { short8 s; u32x4 u; uint4 q; };

// Build combined recurrent matrix M[o][k] (512x512 bf16), scales folded in.
// Also zeroes the flag/xcc region (stream-ordered before rnn_k: replay-safe).
__global__ __launch_bounds__(256) void buildM_k(
    const float* __restrict__ W11, const float* __restrict__ W22,
    const float* __restrict__ W12, const float* __restrict__ W21,
    unsigned short* __restrict__ M, unsigned* __restrict__ ctrl) {
  if (blockIdx.x == 0) {
    #pragma unroll
    for (int i = 0; i < 8; i++) ctrl[threadIdx.x + 256 * i] = 0;  // 8KB
  }
  int idx = blockIdx.x * 256 + threadIdx.x;  // 262144 total
  int o = idx >> 9, k = idx & 511;
  const float A1f = (float)(16.67 / 100.0);
  float v;
  if (o < 256) {
    v = (k < 256) ? A1f * W11[(o << 8) + k]
                  : A1f * 0.5f * W21[(o << 8) + (k - 256)];
  } else {
    int o2 = o - 256;
    v = (k < 256) ? A1f * 0.5f * W12[(o2 << 8) + k]
                  : A1f * W22[(o2 << 8) + (k - 256)];
  }
  M[idx] = f2bf(v);
}

__global__ __launch_bounds__(256) void buildWiT_k(const float* __restrict__ Wi,
                                                  float* __restrict__ WiT) {
  int idx = blockIdx.x * 256 + threadIdx.x;  // 32768 = 128*256, WiT[k][o]
  int k = idx >> 8, o = idx & 255;
  WiT[idx] = Wi[o * 128 + k];
}

// xp'[t][b][o] = A1 * (sum_i x[b][t][i]*Wi[o][i] + bi[o]), f32, layout [t][b][o].
__global__ __launch_bounds__(256) void xproj_k(
    const float* __restrict__ x, const float* __restrict__ WiT,
    const float* __restrict__ bi, float* __restrict__ xp) {
  __shared__ float xs[128 * 68];
  int tid = threadIdx.x;
  int wv = tid >> 6;
  int c = tid & 63;
  long Rbase = (long)blockIdx.x * 64;
  const float* xg = x + Rbase * 128;
  #pragma unroll
  for (int i = 0; i < 32; i++) {
    int idx = tid + 256 * i;
    int r = idx >> 7, k = idx & 127;
    xs[k * 68 + r] = xg[idx];
  }
  __syncthreads();
  float acc[4][16];
  #pragma unroll
  for (int a = 0; a < 4; a++)
    #pragma unroll
    for (int b = 0; b < 16; b++) acc[a][b] = 0.f;
  for (int k = 0; k < 128; k++) {
    f32x4 w4 = *(const f32x4*)(WiT + k * 256 + 4 * c);
    const float* xr = &xs[k * 68 + 16 * wv];
    #pragma unroll
    for (int rr = 0; rr < 4; rr++) {
      f32x4 xv = *(const f32x4*)(xr + 4 * rr);
      #pragma unroll
      for (int cc = 0; cc < 4; cc++) {
        #pragma unroll
        for (int u = 0; u < 4; u++)
          acc[cc][4 * rr + u] = fmaf(w4[cc], xv[u], acc[cc][4 * rr + u]);
      }
    }
  }
  f32x4 bv = *(const f32x4*)(bi + 4 * c);
  const float A1f = (float)(16.67 / 100.0);
  #pragma unroll
  for (int rr = 0; rr < 16; rr++) {
    long R = Rbase + 16 * wv + rr;
    int b = (int)(R >> 10), t = (int)(R & 1023);
    f32x4 o;
    #pragma unroll
    for (int cc = 0; cc < 4; cc++) o[cc] = A1f * (acc[cc][rr] + bv[cc]);
    *(f32x4*)(xp + ((long)(t * 64 + b) << 8) + 4 * c) = o;
  }
}

// Recurrent kernel, OUTPUT-split pair design.
// grid = 16; active bids {0..3} = role 0 (out cols 0..255), {8..11} = role 1
// (cols 256..511); pairing (g, g+8) -> same XCD under bid%8 round-robin.
// Each block: batches 16g..16g+15, its 256 cols over FULL k=512.
// Weights 256KB/block pinned in VGPRs (128/wave, forced live via opaque asm).
// Per step, pair exchanges h-halves (1KB/wave) through L2.
// Phases: A = MFMA own-k (locally produced h) | B = recv partner h -> LDS |
// barrier | C = MFMA partner-k | D = finalize f32, write out + LDS,
// LDS read-back transpose, ship own h-half, xp prefetch | barrier.
__global__ __launch_bounds__(512, 2) void rnn_k(
    const unsigned short* __restrict__ M, const float* __restrict__ xp,
    float* __restrict__ out, char* __restrict__ ws) {
  const int bid = blockIdx.x;
  if (bid & 4) return;
  const int g = bid & 3;
  const int role = bid >> 3;
  const int prole = 1 - role;
  const int tid = threadIdx.x;
  const int w = tid >> 6;
  const int lane = tid & 63;
  const int n = lane & 15;   // MFMA col (neuron) / A row (batch) lane bits
  const int q = lane >> 4;   // 0..3
  const int colbase = role * 256 + w * 32;

  __shared__ __align__(16) unsigned short hb[2][16 * 512];
  __shared__ int sFast;

  {  // zero hb[0] entirely (h(0) = 0): 16KB
    uint4 z = {0, 0, 0, 0};
    uint4* p = (uint4*)&hb[0][0];
    p[tid] = z;
    p[tid + 512] = z;
  }

  unsigned* flags = (unsigned*)(ws + WS_FLAGS);
  unsigned* xcct = (unsigned*)(ws + WS_XCC);
  if (tid == 0) {
    unsigned myx;
    asm volatile("s_getreg_b32 %0, hwreg(HW_REG_XCC_ID)" : "=s"(myx));
    __hip_atomic_store(&xcct[bid], myx + 1, __ATOMIC_RELAXED, __HIP_MEMORY_SCOPE_AGENT);
    unsigned ox;
    while ((ox = __hip_atomic_load(&xcct[bid ^ 8], __ATOMIC_RELAXED,
                                   __HIP_MEMORY_SCOPE_AGENT)) == 0u)
      __builtin_amdgcn_s_sleep(2);
    sFast = (ox == myx + 1) ? 1 : 0;
  }

  const float C1 = (float)(1.0 - 16.67 / 100.0);

  // ---- pinned weights: Bp[nt][kt] = M[col = colbase+nt*16+n][kt*32+q*8 ..+8]
  V128 Bp[2][16];
  #pragma unroll
  for (int nt = 0; nt < 2; nt++) {
    const unsigned short* mb = M + (colbase + nt * 16 + n) * 512 + q * 8;
    #pragma unroll
    for (int kt = 0; kt < 16; kt++) Bp[nt][kt].u = *(const u32x4*)(mb + kt * 32);
  }
  // Opaque-ify: values become asm results -> cannot be rematerialized; the
  // allocator must keep all 128 VGPRs of weights live across the t-loop.
  #pragma unroll
  for (int nt = 0; nt < 2; nt++)
    #pragma unroll
    for (int kt = 0; kt < 16; kt++)
      asm volatile("" : "+v"(Bp[nt][kt].u));

  float hprev[2][4];
  #pragma unroll
  for (int a = 0; a < 2; a++)
    #pragma unroll
    for (int b = 0; b < 4; b++) hprev[a][b] = 0.f;

  const bool hasxp = (role == 0);  // xp feeds cols 0..255 only
  const float* xpb = xp + ((g * 16 + 4 * q) << 8) + colbase + n;
  float xpA[2][4], xpB[2][4];
  #pragma unroll
  for (int a = 0; a < 2; a++)
    #pragma unroll
    for (int b = 0; b < 4; b++) { xpA[a][b] = 0.f; xpB[a][b] = 0.f; }
  if (hasxp) {
    #pragma unroll
    for (int nt = 0; nt < 2; nt++)
      #pragma unroll
      for (int j = 0; j < 4; j++) {
        xpA[nt][j] = __builtin_nontemporal_load(xpb + 0L * 16384 + j * 256 + nt * 16);
        xpB[nt][j] = __builtin_nontemporal_load(xpb + 1L * 16384 + j * 256 + nt * 16);
      }
  }

  float* outb = out + (long)(g * 16 + 4 * q) * (NT * NH) + colbase + n;

  // exchange addressing: slot = (g*2+srcRole)*8 + srcWave; receiver wave w
  // consumes sender wave w's slice (flat tid ordering matches).
  const int sslot = (g * 2 + role) * 8 + w;
  const int rslot = (g * 2 + prole) * 8 + w;
  char* xs_base = ws + WS_X + (sslot * 2) * 1024 + lane * 16;
  char* xr_base = ws + WS_X + (rslot * 2) * 1024 + lane * 16;
  unsigned* fs = flags + sslot * 16;
  unsigned* fr = flags + rslot * 16;

  const int m2 = lane >> 2;  // transpose-slice row (batch), 16 values
  const int oct = lane & 3;  // col octet
  const unsigned eShip = (unsigned)((m2 * 512 + colbase + oct * 8) ^ swzE(m2));
  const unsigned eRecv =
      (unsigned)((m2 * 512 + prole * 256 + w * 32 + oct * 8) ^ swzE(m2));

  __syncthreads();
  const bool fastp = (sFast != 0);

  auto step = [&](unsigned short* hr, unsigned short* hw, int t,
                  float (&xpc)[2][4]) {
    f32x4 acc[2];
    acc[0] = (f32x4){0.f, 0.f, 0.f, 0.f};
    acc[1] = (f32x4){0.f, 0.f, 0.f, 0.f};

    // ---- phase A: MFMA over own k-half (h produced locally last step)
    #pragma unroll
    for (int kt8 = 0; kt8 < 8; kt8++) {
      int kt = role * 8 + kt8;
      unsigned e = (unsigned)((n * 512 + kt * 32 + q * 8) ^ swzE(n));
      short8 a = *(const short8*)(hr + e);
      acc[0] = mfma16(a, Bp[0][kt].s, acc[0]);
      acc[1] = mfma16(a, Bp[1][kt].s, acc[1]);
    }

    // ---- phase B: receive partner h-half -> LDS (skip t=0: zeros pre-set)
    if (t > 0) {
      uint4 pk;
      const char* xb = xr_base + (t & 1) * 1024;
      if (fastp) {
        while (*(volatile const unsigned*)fr < (unsigned)t)
          __builtin_amdgcn_s_sleep(1);
        volatile const unsigned* xv = (volatile const unsigned*)xb;
        pk.x = xv[0]; pk.y = xv[1]; pk.z = xv[2]; pk.w = xv[3];
      } else {
        while (__hip_atomic_load(fr, __ATOMIC_RELAXED,
                                 __HIP_MEMORY_SCOPE_AGENT) < (unsigned)t)
          __builtin_amdgcn_s_sleep(1);
        ull u0 = __hip_atomic_load((const ull*)xb, __ATOMIC_RELAXED,
                                   __HIP_MEMORY_SCOPE_AGENT);
        ull u1 = __hip_atomic_load((const ull*)(xb + 8), __ATOMIC_RELAXED,
                                   __HIP_MEMORY_SCOPE_AGENT);
        pk.x = (unsigned)u0; pk.y = (unsigned)(u0 >> 32);
        pk.z = (unsigned)u1; pk.w = (unsigned)(u1 >> 32);
      }
      *(uint4*)(hr + eRecv) = pk;  // ds_write_b128, swizzled
    }
    asm volatile("s_waitcnt lgkmcnt(0)\n\ts_barrier" ::: "memory");  // barrier 1

    // ---- phase C: MFMA over partner k-half
    #pragma unroll
    for (int kt8 = 0; kt8 < 8; kt8++) {
      int kt = prole * 8 + kt8;
      unsigned e = (unsigned)((n * 512 + kt * 32 + q * 8) ^ swzE(n));
      short8 a = *(const short8*)(hr + e);
      acc[0] = mfma16(a, Bp[0][kt].s, acc[0]);
      acc[1] = mfma16(a, Bp[1][kt].s, acc[1]);
    }

    // ---- phase D: finalize (all f32), store out, write h to LDS, ship
    float* outt = outb + (long)t * NH;
    #pragma unroll
    for (int nt = 0; nt < 2; nt++) {
      #pragma unroll
      for (int j = 0; j < 4; j++) {
        float v = fmaf(hprev[nt][j], C1, acc[nt][j] + xpc[nt][j]);
        v = fmaxf(v, 0.f);
        hprev[nt][j] = v;
        __builtin_nontemporal_store(v, outt + (long)j * (NT * NH) + nt * 16);
        unsigned rr;
        asm("v_cvt_pk_bf16_f32 %0, %1, %2" : "=v"(rr) : "v"(v), "v"(v));
        int mm = 4 * q + j;
        hw[(unsigned)((mm * 512 + colbase + nt * 16 + n) ^ swzE(mm))] =
            (unsigned short)rr;
      }
    }
    // transpose via LDS read-back, ship own h-half slice (16B/lane)
    asm volatile("s_waitcnt lgkmcnt(0)" ::: "memory");
    uint4 pay = *(const uint4*)(hw + eShip);
    char* xb = xs_base + ((t + 1) & 1) * 1024;
    if (fastp) {
      *(uint4*)xb = pay;
      asm volatile("s_waitcnt vmcnt(0)" ::: "memory");
      if (lane == 0) *(volatile unsigned*)fs = (unsigned)(t + 1);
    } else {
      ull u0 = (ull)pay.x | ((ull)pay.y << 32);
      ull u1 = (ull)pay.z | ((ull)pay.w << 32);
      __hip_atomic_store((ull*)xb, u0, __ATOMIC_RELAXED, __HIP_MEMORY_SCOPE_AGENT);
      __hip_atomic_store((ull*)(xb + 8), u1, __ATOMIC_RELAXED,
                         __HIP_MEMORY_SCOPE_AGENT);
      if (lane == 0)
        __hip_atomic_store(fs, (unsigned)(t + 1), __ATOMIC_RELEASE,
                           __HIP_MEMORY_SCOPE_AGENT);
    }
    // xp prefetch for t+2 into the buffer just consumed
    if (hasxp) {
      int tn = t + 2; if (tn >= NT) tn = 0;  // wrap: values unused, stay valid
      const float* xpl = xpb + (long)tn * 16384;
      #pragma unroll
      for (int nt = 0; nt < 2; nt++)
        #pragma unroll
        for (int j = 0; j < 4; j++)
          xpc[nt][j] = __builtin_nontemporal_load(xpl + j * 256 + nt * 16);
    }
    asm volatile("s_waitcnt lgkmcnt(0)\n\ts_barrier" ::: "memory");  // barrier 2
  };

  #pragma unroll 1
  for (int t = 0; t < NT; t += 2) {
    step(hb[0], hb[1], t, xpA);
    step(hb[1], hb[0], t + 1, xpB);
  }

  // final h1, h2 (each wave owns its 32 cols)
  const long fbase = (long)NB * NT * NH;  // 33554432
  #pragma unroll
  for (int nt = 0; nt < 2; nt++) {
    #pragma unroll
    for (int j = 0; j < 4; j++) {
      int b = g * 16 + 4 * q + j;
      int col = colbase + nt * 16 + n;
      long off = (col < 256) ? (fbase + b * 256 + col)
                             : (fbase + 16384 + b * 256 + (col - 256));
      out[off] = hprev[nt][j];
    }
  }
}

extern "C" void kernel_launch(void* const* d_in, const int* in_sizes, int n_in,
                              void* d_out, int out_size, void* d_ws, size_t ws_size,
                              hipStream_t stream) {
  const float* x   = (const float*)d_in[0];
  const float* Wi  = (const float*)d_in[2];
  const float* bi  = (const float*)d_in[3];
  const float* W11 = (const float*)d_in[4];
  const float* W22 = (const float*)d_in[5];
  const float* W12 = (const float*)d_in[6];
  const float* W21 = (const float*)d_in[7];
  float* out = (float*)d_out;

  unsigned short* M = (unsigned short*)d_ws;
  float* WiT = (float*)((char*)d_ws + 524288);
  unsigned* ctrl = (unsigned*)((char*)d_ws + WS_FLAGS);
  float* xp = (float*)((char*)d_ws + WS_XP);

  buildM_k<<<1024, 256, 0, stream>>>(W11, W22, W12, W21, M, ctrl);
  buildWiT_k<<<128, 256, 0, stream>>>(Wi, WiT);
  xproj_k<<<1024, 256, 0, stream>>>(x, WiT, bi, xp);
  rnn_k<<<16, 512, 0, stream>>>(M, xp, out, (char*)d_ws);
}